// Round 9
// baseline (834.265 us; speedup 1.0000x reference)
//
#include <hip/hip_runtime.h>
#include <hip/hip_bf16.h>
#include <stdint.h>

#define NV 300000
#define KOFF 27
#define BM 128

typedef __bf16 bf16x8 __attribute__((ext_vector_type(8)));
typedef float f32x4 __attribute__((ext_vector_type(4)));
typedef unsigned short u16;

__device__ __forceinline__ u16 f2bf(float f) {
  uint32_t u = __float_as_uint(f);
  uint32_t r = (u + 0x7fffu + ((u >> 16) & 1u)) >> 16;
  return (u16)r;
}

// ---- convert x (f32) -> bf16 table ----
__global__ void cvt_x_kernel(const float* __restrict__ x, u16* __restrict__ xb,
                             int n) {
  int i = (blockIdx.x * 256 + threadIdx.x) * 8;
  if (i >= n) return;
  const float4 a = *(const float4*)(x + i);
  const float4 b = *(const float4*)(x + i + 4);
  uint4 o;
  o.x = (uint32_t)f2bf(a.x) | ((uint32_t)f2bf(a.y) << 16);
  o.y = (uint32_t)f2bf(a.z) | ((uint32_t)f2bf(a.w) << 16);
  o.z = (uint32_t)f2bf(b.x) | ((uint32_t)f2bf(b.y) << 16);
  o.w = (uint32_t)f2bf(b.z) | ((uint32_t)f2bf(b.w) << 16);
  *(uint4*)(xb + i) = o;
}

// ---- convert W -> bf16, FRAG-MAJOR: Wt2[k][s=n*2+c2][lane] (16B/lane) ----
__global__ void cvt_w_kernel(const float* __restrict__ W0,
                             const float* __restrict__ W1,
                             u16* __restrict__ W0t, u16* __restrict__ W1t) {
  int t = blockIdx.x * 256 + threadIdx.x;  // 27648 total
  const float* W = W0;
  u16* Wt = W0t;
  if (t >= 13824) { W = W1; Wt = W1t; t -= 13824; }
  const int l = t & 63;
  const int s = (t >> 6) & 7;
  const int k = t >> 9;  // 0..26
  const int co = (s >> 1) * 16 + (l & 15);
  const int ci0 = ((s & 1) * 4 + (l >> 4)) * 8;
  u16 h[8];
#pragma unroll
  for (int j = 0; j < 8; j++)
    h[j] = f2bf(W[((size_t)k * 64 + ci0 + j) * 64 + co]);
  uint4 o;
  o.x = (uint32_t)h[0] | ((uint32_t)h[1] << 16);
  o.y = (uint32_t)h[2] | ((uint32_t)h[3] << 16);
  o.z = (uint32_t)h[4] | ((uint32_t)h[5] << 16);
  o.w = (uint32_t)h[6] | ((uint32_t)h[7] << 16);
  *(uint4*)(Wt + (size_t)k * 4096 + s * 512 + (size_t)l * 8) = o;
}

// ---- barrier-free gather-GEMM conv, REGISTER-staged gathers ----
// Gather path goes through the TA coalescer (global_load_dwordx4 per lane,
// 8 lanes contiguous per row) instead of the global_load_lds DMA path.
// T14 split: gather(k+2) issued a full tile before its ds_write; no inline
// asm — compiler places exact waits against register dependencies.
template <int MODE>
__global__ __launch_bounds__(256, 2) void conv_kernel(
    const u16* __restrict__ tab,   // [NV][64] bf16
    const u16* __restrict__ Wt,    // [27][8][64] frag-major bf16
    const float* __restrict__ bias,
    const int* __restrict__ nbr,   // [27][NV]
    const float* __restrict__ resid, void* __restrict__ outp) {
  __shared__ __align__(16) u16 lsA[2][4][32 * 64];  // 2 bufs x 4 waves x 4KB
  const int t = threadIdx.x;
  const int w = t >> 6;
  const int l = t & 63;
  const int lq = l >> 4;
  const int lr = l & 15;
  const int row0 = blockIdx.x * BM + w * 32;

  f32x4 acc[2][4] = {};
  float bv[4];
#pragma unroll
  for (int n = 0; n < 4; n++) bv[n] = bias[n * 16 + lr];

  u16* p0 = &lsA[0][w][0];
  u16* p1 = &lsA[1][w][0];

  int iA[4];
  uint4 g[4];
  bf16x8 bA[8], bB[8];

  const int rbase = row0 + (l >> 3);
  auto loadIdx4 = [&](int k, int* d) {
    const size_t ko = (size_t)(k < KOFF ? k : KOFF - 1) * NV;
#pragma unroll
    for (int q = 0; q < 4; q++) {
      int gr = rbase + q * 8;
      if (gr >= NV) gr = NV - 1;
      d[q] = __builtin_nontemporal_load(nbr + ko + gr);
    }
  };

  const int seg = (l & 7) ^ ((l >> 3) & 7);  // XOR pre-swizzle, const per lane
  // per-lane register gather: lane l covers row q*8+(l>>3), 16B chunk `seg`
  auto gatherRegs = [&](const int* idx, uint4* gg) {
#pragma unroll
    for (int q = 0; q < 4; q++)
      gg[q] = *(const uint4*)(tab + (size_t)idx[q] * 64 + seg * 8);
  };
  // LDS layout identical to the old global_load_lds dest: slot q, byte l*16
  auto writeStage = [&](u16* dst, const uint4* gg) {
#pragma unroll
    for (int q = 0; q < 4; q++)
      *(uint4*)(dst + q * 512 + (size_t)l * 8) = gg[q];
  };

  auto loadB = [&](bf16x8* b, int k) {
    const u16* B =
        Wt + (size_t)(k < KOFF ? k : KOFF - 1) * 4096 + (size_t)l * 8;
#pragma unroll
    for (int s = 0; s < 8; s++) b[s] = *(const bf16x8*)(B + s * 512);
  };

  auto compute = [&](const u16* A, const bf16x8* b) {
    bf16x8 af[2][2];
#pragma unroll
    for (int m = 0; m < 2; m++) {
      const int row = m * 16 + lr;
      const u16* Ar = A + row * 64;
#pragma unroll
      for (int c2 = 0; c2 < 2; c2++) {
        const int c = c2 * 4 + lq;
        af[m][c2] = *(const bf16x8*)(Ar + ((c ^ (row & 7)) * 8));
      }
    }
#pragma unroll
    for (int m = 0; m < 2; m++)
#pragma unroll
      for (int n = 0; n < 4; n++)
#pragma unroll
        for (int c2 = 0; c2 < 2; c2++)
          acc[m][n] = __builtin_amdgcn_mfma_f32_16x16x32_bf16(
              af[m][c2], b[n * 2 + c2], acc[m][n], 0, 0, 0);
  };

  // prologue: A(0) staged; A(1) in regs; idx(2) loading; B(0) in regs
  loadIdx4(0, iA);
  gatherRegs(iA, g);
  loadIdx4(1, iA);
  writeStage(p0, g);   // A(0) -> LDS
  gatherRegs(iA, g);   // A(1) -> regs
  loadIdx4(2, iA);
  loadB(bA, 0);

#pragma unroll 1
  for (int k = 0; k < KOFF - 1; k += 2) {  // pairs (0,1)...(24,25)
    // even sub-iter: tile k in p0/bA; g holds A(k+1); iA holds idx(k+2)
    writeStage(p1, g);       // A(k+1) -> LDS
    gatherRegs(iA, g);       // A(k+2) -> regs (in flight across compute)
    loadIdx4(k + 3, iA);     // idx(k+3)
    loadB(bB, k + 1);
    compute(p0, bA);
    // odd sub-iter: tile k+1 in p1/bB; g holds A(k+2); iA holds idx(k+3)
    writeStage(p0, g);       // A(k+2) -> LDS
    gatherRegs(iA, g);       // A(k+3) -> regs (k=24: clamped dup, harmless)
    loadIdx4(k + 4, iA);
    loadB(bA, k + 2);
    compute(p1, bB);
  }
  // tail: tile 26 in p0/bA
  compute(p0, bA);

  // epilogue: C/D layout col=lane&15, row=(lane>>4)*4+j  [m89]
#pragma unroll
  for (int m = 0; m < 2; m++) {
#pragma unroll
    for (int n = 0; n < 4; n++) {
      const int col = n * 16 + lr;
#pragma unroll
      for (int j = 0; j < 4; j++) {
        const int row = row0 + m * 16 + lq * 4 + j;
        if (row < NV) {
          float v = acc[m][n][j] + bv[n];
          if (MODE == 0) {
            ((u16*)outp)[(size_t)row * 64 + col] = f2bf(v < 0.f ? 0.f : v);
          } else {
            ((float*)outp)[(size_t)row * 64 + col] =
                v + resid[(size_t)row * 64 + col];
          }
        }
      }
    }
  }
}

extern "C" void kernel_launch(void* const* d_in, const int* in_sizes, int n_in,
                              void* d_out, int out_size, void* d_ws,
                              size_t ws_size, hipStream_t stream) {
  const float* x = (const float*)d_in[0];
  const float* W0 = (const float*)d_in[1];
  const float* b0 = (const float*)d_in[2];
  const float* W1 = (const float*)d_in[3];
  const float* b1 = (const float*)d_in[4];
  const int* nbr = (const int*)d_in[5];

  // ws layout: xb 38.4MB | midb 38.4MB | W0t 216KB | W1t 216KB
  if (ws_size < 77242368) return;
  char* ws = (char*)d_ws;
  u16* xb = (u16*)(ws);
  u16* midb = (u16*)(ws + 38400000);
  u16* W0t = (u16*)(ws + 76800000);
  u16* W1t = (u16*)(ws + 77021184);

  cvt_w_kernel<<<108, 256, 0, stream>>>(W0, W1, W0t, W1t);
  cvt_x_kernel<<<9375, 256, 0, stream>>>(x, xb, NV * 64);

  const int nblk = (NV + BM - 1) / BM;  // 2344
  conv_kernel<0><<<nblk, 256, 0, stream>>>(xb, W0t, b0, nbr, nullptr, midb);
  conv_kernel<1><<<nblk, 256, 0, stream>>>(midb, W1t, b1, nbr, x, d_out);
}

// Round 10
// 366.389 us; speedup vs baseline: 2.2770x; 2.2770x over previous
//
#include <hip/hip_runtime.h>
#include <hip/hip_bf16.h>
#include <stdint.h>

#define NV 300000
#define KOFF 27
#define BM 128

typedef __bf16 bf16x8 __attribute__((ext_vector_type(8)));
typedef float f32x4 __attribute__((ext_vector_type(4)));
typedef unsigned short u16;

__device__ __forceinline__ u16 f2bf(float f) {
  uint32_t u = __float_as_uint(f);
  uint32_t r = (u + 0x7fffu + ((u >> 16) & 1u)) >> 16;
  return (u16)r;
}

__device__ __forceinline__ void async16(const void* g, void* l) {
  __builtin_amdgcn_global_load_lds(
      (const __attribute__((address_space(1))) uint32_t*)g,
      (__attribute__((address_space(3))) uint32_t*)l, 16, 0, 0);
}

// ---- convert x (f32) -> bf16 table ----
__global__ void cvt_x_kernel(const float* __restrict__ x, u16* __restrict__ xb,
                             int n) {
  int i = (blockIdx.x * 256 + threadIdx.x) * 8;
  if (i >= n) return;
  const float4 a = *(const float4*)(x + i);
  const float4 b = *(const float4*)(x + i + 4);
  uint4 o;
  o.x = (uint32_t)f2bf(a.x) | ((uint32_t)f2bf(a.y) << 16);
  o.y = (uint32_t)f2bf(a.z) | ((uint32_t)f2bf(a.w) << 16);
  o.z = (uint32_t)f2bf(b.x) | ((uint32_t)f2bf(b.y) << 16);
  o.w = (uint32_t)f2bf(b.z) | ((uint32_t)f2bf(b.w) << 16);
  *(uint4*)(xb + i) = o;
}

// ---- convert W -> bf16, FRAG-MAJOR: Wt2[k][s=n*2+c2][lane] (16B/lane) ----
__global__ void cvt_w_kernel(const float* __restrict__ W0,
                             const float* __restrict__ W1,
                             u16* __restrict__ W0t, u16* __restrict__ W1t) {
  int t = blockIdx.x * 256 + threadIdx.x;  // 27648 total
  const float* W = W0;
  u16* Wt = W0t;
  if (t >= 13824) { W = W1; Wt = W1t; t -= 13824; }
  const int l = t & 63;
  const int s = (t >> 6) & 7;
  const int k = t >> 9;  // 0..26
  const int co = (s >> 1) * 16 + (l & 15);
  const int ci0 = ((s & 1) * 4 + (l >> 4)) * 8;
  u16 h[8];
#pragma unroll
  for (int j = 0; j < 8; j++)
    h[j] = f2bf(W[((size_t)k * 64 + ci0 + j) * 64 + co]);
  uint4 o;
  o.x = (uint32_t)h[0] | ((uint32_t)h[1] << 16);
  o.y = (uint32_t)h[2] | ((uint32_t)h[3] << 16);
  o.z = (uint32_t)h[4] | ((uint32_t)h[5] << 16);
  o.w = (uint32_t)h[6] | ((uint32_t)h[7] << 16);
  *(uint4*)(Wt + (size_t)k * 4096 + s * 512 + (size_t)l * 8) = o;
}

// ---- barrier-free, 2-deep-pipelined gather-GEMM conv (best: R4) ----
// Wave-private A tiles (3 LDS buffers, XOR-swizzled), B frags in registers
// (double-buffered, coalesced frag-major loads), idx 2 iterations ahead.
// 16 vmem issues per sub-iter between asm walls => s_waitcnt vmcnt(24)
// retires stage(k)+B(k), keeps 2 younger generations in flight.
template <int MODE>
__global__ __launch_bounds__(256, 2) void conv_kernel(
    const u16* __restrict__ tab,   // [NV][64] bf16
    const u16* __restrict__ Wt,    // [27][8][64] frag-major bf16
    const float* __restrict__ bias,
    const int* __restrict__ nbr,   // [27][NV]
    const float* __restrict__ resid, void* __restrict__ outp) {
  __shared__ __align__(16) u16 lsA[3][4][32 * 64];  // 3 bufs x 4 waves x 4KB
  const int t = threadIdx.x;
  const int w = t >> 6;
  const int l = t & 63;
  const int lq = l >> 4;
  const int lr = l & 15;
  const int row0 = blockIdx.x * BM + w * 32;

  f32x4 acc[2][4] = {};
  float bv[4];
#pragma unroll
  for (int n = 0; n < 4; n++) bv[n] = bias[n * 16 + lr];

  u16* p0 = &lsA[0][w][0];
  u16* p1 = &lsA[1][w][0];
  u16* p2 = &lsA[2][w][0];

  int iT0[4], iT1[4], iA[4], iB[4];
  bf16x8 bA[8], bB[8];

  const int rbase = row0 + (l >> 3);
  auto loadIdx4 = [&](int k, int* d) {
    const size_t ko = (size_t)(k < KOFF ? k : KOFF - 1) * NV;
#pragma unroll
    for (int q = 0; q < 4; q++) {
      int gr = rbase + q * 8;
      if (gr >= NV) gr = NV - 1;
      d[q] = nbr[ko + gr];
    }
  };

  const int seg = (l & 7) ^ ((l >> 3) & 7);  // pre-swizzle, const per lane
  auto stageA = [&](u16* dst, const int* idx) {
#pragma unroll
    for (int q = 0; q < 4; q++)
      async16(tab + (size_t)idx[q] * 64 + seg * 8, (char*)dst + q * 1024);
  };

  auto loadB = [&](bf16x8* b, int k) {
    const u16* B =
        Wt + (size_t)(k < KOFF ? k : KOFF - 1) * 4096 + (size_t)l * 8;
#pragma unroll
    for (int s = 0; s < 8; s++) b[s] = *(const bf16x8*)(B + s * 512);
  };

  auto compute = [&](const u16* A, const bf16x8* b) {
    bf16x8 af[2][2];
#pragma unroll
    for (int m = 0; m < 2; m++) {
      const int row = m * 16 + lr;
      const u16* Ar = A + row * 64;
#pragma unroll
      for (int c2 = 0; c2 < 2; c2++) {
        const int c = c2 * 4 + lq;
        af[m][c2] = *(const bf16x8*)(Ar + ((c ^ (row & 7)) * 8));
      }
    }
#pragma unroll
    for (int m = 0; m < 2; m++)
#pragma unroll
      for (int n = 0; n < 4; n++)
#pragma unroll
        for (int c2 = 0; c2 < 2; c2++)
          acc[m][n] = __builtin_amdgcn_mfma_f32_16x16x32_bf16(
              af[m][c2], b[n * 2 + c2], acc[m][n], 0, 0, 0);
  };

  // prologue — grouped by asm walls so the wall-1 count math is order-robust
  loadIdx4(0, iT0);
  loadIdx4(1, iT1);
  loadIdx4(2, iA);
  asm volatile("" ::: "memory");
  stageA(p0, iT0);   // A(0)
  loadB(bA, 0);      // B(0)
  asm volatile("" ::: "memory");
  loadIdx4(3, iB);
  asm volatile("" ::: "memory");
  stageA(p1, iT1);   // A(1)

#pragma unroll 1
  for (int k = 0; k < KOFF - 1; k += 2) {
    // ---- sub-iter k: issues {B(k+1):8, A(k+2):4, i(k+4):4} ----
    loadB(bB, k + 1);
    stageA(p2, iA);          // auto-wait retires iA (i(k+2)) only
    loadIdx4(k + 4, iA);
    asm volatile("s_waitcnt vmcnt(24)" ::: "memory");  // retires A(k), B(k)
    __builtin_amdgcn_sched_barrier(0);
    compute(p0, bA);
    // ---- sub-iter k+1: issues {B(k+2):8, A(k+3):4, i(k+5):4} ----
    loadB(bA, k + 2);
    stageA(p0, iB);          // auto-wait retires iB (i(k+3))
    loadIdx4(k + 5, iB);
    asm volatile("s_waitcnt vmcnt(24)" ::: "memory");  // retires A(k+1), B(k+1)
    __builtin_amdgcn_sched_barrier(0);
    compute(p1, bB);
    // rotate: new (p0,p1,p2) = (old p2, old p0, old p1)
    u16* tmp = p0;
    p0 = p2;
    p2 = p1;
    p1 = tmp;
  }
  // tail k=26: p0 holds A(26), bA holds B(26)
  asm volatile("s_waitcnt vmcnt(0)" ::: "memory");
  __builtin_amdgcn_sched_barrier(0);
  compute(p0, bA);

  // epilogue: C/D layout col=lane&15, row=(lane>>4)*4+j  [m89]
#pragma unroll
  for (int m = 0; m < 2; m++) {
#pragma unroll
    for (int n = 0; n < 4; n++) {
      const int col = n * 16 + lr;
#pragma unroll
      for (int j = 0; j < 4; j++) {
        const int row = row0 + m * 16 + lq * 4 + j;
        if (row < NV) {
          float v = acc[m][n][j] + bv[n];
          if (MODE == 0) {
            ((u16*)outp)[(size_t)row * 64 + col] = f2bf(v < 0.f ? 0.f : v);
          } else {
            ((float*)outp)[(size_t)row * 64 + col] =
                v + resid[(size_t)row * 64 + col];
          }
        }
      }
    }
  }
}

extern "C" void kernel_launch(void* const* d_in, const int* in_sizes, int n_in,
                              void* d_out, int out_size, void* d_ws,
                              size_t ws_size, hipStream_t stream) {
  const float* x = (const float*)d_in[0];
  const float* W0 = (const float*)d_in[1];
  const float* b0 = (const float*)d_in[2];
  const float* W1 = (const float*)d_in[3];
  const float* b1 = (const float*)d_in[4];
  const int* nbr = (const int*)d_in[5];

  // ws layout: xb 38.4MB | midb 38.4MB | W0t 216KB | W1t 216KB
  if (ws_size < 77242368) return;
  char* ws = (char*)d_ws;
  u16* xb = (u16*)(ws);
  u16* midb = (u16*)(ws + 38400000);
  u16* W0t = (u16*)(ws + 76800000);
  u16* W1t = (u16*)(ws + 77021184);

  cvt_w_kernel<<<108, 256, 0, stream>>>(W0, W1, W0t, W1t);
  cvt_x_kernel<<<9375, 256, 0, stream>>>(x, xb, NV * 64);

  const int nblk = (NV + BM - 1) / BM;  // 2344
  conv_kernel<0><<<nblk, 256, 0, stream>>>(xb, W0t, b0, nbr, nullptr, midb);
  conv_kernel<1><<<nblk, 256, 0, stream>>>(midb, W1t, b1, nbr, x, d_out);
}